// Round 8
// baseline (221.644 us; speedup 1.0000x reference)
//
#include <hip/hip_runtime.h>
#include <math.h>

#define NELEM 1048576    // B*C*H*W
#define TILE 256         // elements per block
#define NBLK (NELEM / TILE)   // 4096
#define LOG2E 1.44269504088896340736f
#define LN2   0.69314718055994530942f

typedef float f32x4 __attribute__((ext_vector_type(4)));
typedef const __attribute__((address_space(1))) void g_void;
typedef __attribute__((address_space(3))) void l_void;

#define AUX_NT 2   // CPol NT bit (gfx940+): evict-first / no-allocate policy

// R4 structure (LDS-DMA staging of pi/mu/s) but with NT cache policy on the
// DMA (aux=2) and on the direct loads. Tests whether the ~4.2 TB/s read rate
// is a path-independent fabric cap or a VMEM-queue-depth limit.
__global__ __launch_bounds__(256) void coupling_kernel(
    const float* __restrict__ x_change, const float* __restrict__ x_id,
    const float* __restrict__ a, const float* __restrict__ b,
    const float* __restrict__ pi, const float* __restrict__ mu,
    const float* __restrict__ s, float* __restrict__ out) {
    __shared__ __align__(16) float ldsP[TILE * 16];
    __shared__ __align__(16) float ldsM[TILE * 16];
    __shared__ __align__(16) float ldsS[TILE * 16];

    const int t = threadIdx.x;
    const int w = t >> 6;          // wave 0..3
    const int l = t & 63;          // lane
    const int e0 = blockIdx.x * TILE;

    // ---- async NT DMA: each wave stages 4 KB per array (4 chunks x 1 KB) ----
    {
        const size_t gbase = (size_t)e0 * 16 + (size_t)(w * 1024 + l * 4);
        const int lbase = w * 1024 + l * 4;
#pragma unroll
        for (int c = 0; c < 4; ++c) {
            __builtin_amdgcn_global_load_lds((g_void*)(pi + gbase + c * 256),
                                             (l_void*)(ldsP + lbase + c * 256), 16, 0, AUX_NT);
            __builtin_amdgcn_global_load_lds((g_void*)(mu + gbase + c * 256),
                                             (l_void*)(ldsM + lbase + c * 256), 16, 0, AUX_NT);
            __builtin_amdgcn_global_load_lds((g_void*)(s + gbase + c * 256),
                                             (l_void*)(ldsS + lbase + c * 256), 16, 0, AUX_NT);
        }
    }

    // ---- small direct loads (NT) overlap the DMA ----
    const int kq = t & 3;          // component-quad owned by this lane
    const int g = t >> 2;          // element group (0..63)
    float xv[4], av[4], bv[4];
#pragma unroll
    for (int p = 0; p < 4; ++p) {
        const int e = e0 + p * 64 + g;
        xv[p] = __builtin_nontemporal_load(x_change + e);
        av[p] = __builtin_nontemporal_load(a + e);
        bv[p] = __builtin_nontemporal_load(b + e);
    }
    if (t < 64) {   // identity passthrough, float4-coalesced
        ((f32x4*)(out + NELEM + e0))[t] =
            __builtin_nontemporal_load((const f32x4*)(x_id + e0) + t);
    }

    __builtin_amdgcn_s_waitcnt(0);                 // drain DMA before barrier
    __syncthreads();

    // ---- compute: 4 passes of 64 elements; lane handles 4 components ----
    float ldj = 0.0f;
    const f32x4* P4 = (const f32x4*)ldsP;
    const f32x4* M4 = (const f32x4*)ldsM;
    const f32x4* S4 = (const f32x4*)ldsS;
#pragma unroll
    for (int p = 0; p < 4; ++p) {
        const int idx = (p * 64 + g) * 4 + kq;     // contiguous across lanes
        const f32x4 pv = P4[idx];
        const f32x4 mv = M4[idx];
        const f32x4 sv = S4[idx];
        const float x = xv[p];

        float psum = 0.0f, cdf = 0.0f, omu = 0.0f, pdf = 0.0f;
#pragma unroll
        for (int j = 0; j < 4; ++j) {
            const float wk = __builtin_amdgcn_exp2f(pv[j] * LOG2E);   // e^pi (pi~N(0,1), safe unnormalized)
            const float ez = __builtin_amdgcn_exp2f(-sv[j] * LOG2E);  // e^{-s}
            const float z = (x - mv[j]) * ez;
            const float enz = __builtin_amdgcn_exp2f(-z * LOG2E);     // e^{-z}
            const float gg = __builtin_amdgcn_rcpf(1.0f + enz);       // sigmoid(z)
            const float wg = wk * gg;
            psum += wk;                      // Σ w
            cdf += wg;                       // Σ w·g
            omu += wg * enz;                 // Σ w·(1-g)
            pdf += wk * ez * gg * gg * enz;  // Σ w·e^{-s}·g·(1-g)
        }
        psum += __shfl_xor(psum, 1); psum += __shfl_xor(psum, 2);
        cdf  += __shfl_xor(cdf, 1);  cdf  += __shfl_xor(cdf, 2);
        omu  += __shfl_xor(omu, 1);  omu  += __shfl_xor(omu, 2);
        pdf  += __shfl_xor(pdf, 1);  pdf  += __shfl_xor(pdf, 2);

        if (kq == 0) {
            const float l2ps = __builtin_amdgcn_logf(psum);
            const float l2c  = __builtin_amdgcn_logf(cdf);
            const float l2o  = __builtin_amdgcn_logf(fmaxf(omu, 1e-38f));
            const float l2p  = __builtin_amdgcn_logf(fmaxf(pdf, 1e-38f));
            // out = (log_cdf - log(1-u) + b)*e^a ; psum cancels in the diff
            out[e0 + p * 64 + g] = ((l2c - l2o) * LN2 + bv[p]) *
                                   __builtin_amdgcn_exp2f(av[p] * LOG2E);
            // ldj = log_pdf - log_cdf - log(1-u) + a
            ldj += (l2p + l2ps - l2c - l2o) * LN2 + av[p];
        }
    }

    // ---- block reduction; block (256 elems) lies within one batch ----
    float v = ldj;
#pragma unroll
    for (int off = 32; off > 0; off >>= 1) v += __shfl_down(v, off);
    __shared__ float ws[4];
    if ((t & 63) == 0) ws[w] = v;
    __syncthreads();
    if (t == 0) {
        const float tot = ws[0] + ws[1] + ws[2] + ws[3];
        const int batch = blockIdx.x >> 7;   // 128 blocks (256 elems each) per batch
        atomicAdd(out + 2 * (size_t)NELEM + batch, tot);
    }
}

extern "C" void kernel_launch(void* const* d_in, const int* in_sizes, int n_in,
                              void* d_out, int out_size, void* d_ws, size_t ws_size,
                              hipStream_t stream) {
    const float* x_change = (const float*)d_in[0];
    const float* x_id     = (const float*)d_in[1];
    const float* sldj     = (const float*)d_in[2];
    const float* a        = (const float*)d_in[3];
    const float* b        = (const float*)d_in[4];
    const float* pi       = (const float*)d_in[5];
    const float* mu       = (const float*)d_in[6];
    const float* s        = (const float*)d_in[7];
    float* out = (float*)d_out;

    const int B = in_sizes[2];

    // Seed sldj output region (harness poisons d_out) with a tiny d2d copy;
    // the kernel atomically accumulates into it (stream-ordered).
    hipMemcpyAsync(out + 2 * (size_t)NELEM, sldj, B * sizeof(float),
                   hipMemcpyDeviceToDevice, stream);

    coupling_kernel<<<NBLK, 256, 0, stream>>>(x_change, x_id, a, b, pi, mu, s, out);
}